// Round 6
// baseline (1301.469 us; speedup 1.0000x reference)
//
#include <hip/hip_runtime.h>
#include <hip/hip_cooperative_groups.h>
#include <math.h>

#define BB 32
#define HH 128
#define WW 128
#define CC 64
#define MX 16
#define MY 16
#define NKX 32   // kx modes: 0..15 and 112..127

#define TWOPI 6.283185307179586f

namespace cg = cooperative_groups;

typedef __attribute__((ext_vector_type(8))) short bf16x8;
typedef __attribute__((ext_vector_type(4))) float f32x4;

__device__ inline unsigned short f2bf(float f) {
    union { float f; unsigned u; } v; v.f = f;
    unsigned r = v.u + 0x7FFFu + ((v.u >> 16) & 1u);   // RTNE
    return (unsigned short)(r >> 16);
}

// ws layout (shorts):
//   FR  [4608 slots][8]   : precomputed bf16 fragments (FA / FB / FD / FEAT / FEBK)
//   X1  [32][16][128][2][64]   X2 [32][32][16][128]   G [32][32][16][128]
//   Zf  [32][128][4][512]  (kE B-frag layout)
// Fragment convention (verified rounds 2-5):
//   A-frag: lane l=(q=l>>4, r=l&15) holds A[row=r][k=q*8+e]
//   B-frag: lane l holds B[k=q*8+e][col=r]
//   C/D   : acc[j] -> row=q*4+j, col=r

// ---------------- kT: build all block-invariant fragments ----------------
__global__ __launch_bounds__(256) void kT(const float* __restrict__ K, unsigned short* __restrict__ FR) {
    __shared__ float2 tw[128];
    int tid = threadIdx.x;
    if (tid < 128) {
        float s, c;
        sincosf(TWOPI * (float)tid * (1.0f / 128.0f), &s, &c);
        tw[tid] = make_float2(c, s);
    }
    __syncthreads();
    int g = blockIdx.x * 256 + tid;       // 0..4607
    short v[8];
    if (g < 512) {                        // FA: A[row=2ky+ri][w]
        int s = g;
        int l = s & 63, ks = (s >> 6) & 3, mt = s >> 8;
        int q = l >> 4, r = l & 15;
        int row = mt * 16 + r, ky = row >> 1, ri = row & 1;
        int k0 = ks * 32 + q * 8;
        #pragma unroll
        for (int e = 0; e < 8; ++e) {
            float2 t = tw[(ky * (k0 + e)) & 127];
            v[e] = (short)f2bf(ri ? -t.y : t.x);
        }
    } else if (g < 2560) {                // FB: A[row=2kxi+rr][k=2h+ri]
        int s = g - 512;
        int l = s & 63, ks = (s >> 6) & 7, mt = s >> 9;
        int q = l >> 4, r = l & 15;
        int row = mt * 16 + r, kxi = row >> 1, rr = row & 1;
        int kx = (kxi < 16) ? kxi : (96 + kxi);
        int k0 = ks * 32 + q * 8;
        #pragma unroll
        for (int e = 0; e < 8; ++e) {
            int k = k0 + e, h = k >> 1, ri = k & 1;
            float2 t = tw[(kx * h) & 127];
            float val = (rr == 0) ? (ri == 0 ? t.x : t.y) : (ri == 0 ? -t.y : t.x);
            v[e] = (short)f2bf(val);
        }
    } else if (g < 3584) {                // FD: A[row=h][k=2kxi+ri]
        int s = g - 2560;
        int l = s & 63, ks = (s >> 6) & 1, mt = s >> 7;
        int q = l >> 4, r = l & 15;
        int h = mt * 16 + r;
        int k0 = ks * 32 + q * 8;
        #pragma unroll
        for (int e = 0; e < 8; ++e) {
            int k = k0 + e, kxi = k >> 1, ri = k & 1;
            int kx = (kxi < 16) ? kxi : (96 + kxi);
            float2 t = tw[(kx * h) & 127];
            v[e] = (short)f2bf(ri == 0 ? t.x : -t.y);
        }
    } else if (g < 4096) {                // FEAT: kE A ks=2 (inverse-ky twiddles, scaled)
        int s = g - 3584;
        int l = s & 63, tm = s >> 6;
        int q = l >> 4, r = l & 15;
        int row = tm * 16 + r;
        const float inv = 1.0f / 16384.0f;
        #pragma unroll
        for (int e = 0; e < 8; ++e) {
            int ky = 4 * q + (e >> 1);
            float sc = ((ky == 0) ? 1.0f : 2.0f) * inv;
            float2 t = tw[(ky * row) & 127];
            v[e] = (short)f2bf((e & 1) ? (-t.y * sc) : (t.x * sc));
        }
    } else {                              // FEBK: kE B ks=0,1 (dense kernel K)
        int s = g - 4096;
        int l = s & 63, ks = (s >> 6) & 1, nt = s >> 7;
        int q = l >> 4, r = l & 15;
        int col = nt * 16 + r;
        #pragma unroll
        for (int e = 0; e < 8; ++e) {
            int k = ks * 32 + q * 8 + e;
            v[e] = (short)f2bf(K[k * CC + col]);
        }
    }
    *(bf16x8*)&FR[(size_t)g * 8] = *(const bf16x8*)v;
}

// ======================= fused cooperative kernel =======================
__global__ __launch_bounds__(256, 4) void kFused(
        const float* __restrict__ x,
        const float* __restrict__ w1r, const float* __restrict__ w1i,
        const float* __restrict__ w2r, const float* __restrict__ w2i,
        const float* __restrict__ bias,
        const unsigned short* __restrict__ FR,
        unsigned short* __restrict__ X1, unsigned short* __restrict__ X2,
        unsigned short* __restrict__ G, unsigned short* __restrict__ Zf,
        float* __restrict__ out) {
    cg::grid_group grid = cg::this_grid();
    __shared__ __align__(16) char smem[34816];
    int tid = threadIdx.x, blk = blockIdx.x;
    int lane = tid & 63, wid = tid >> 6, q = lane >> 4, r = lane & 15;

    // ---------------- Stage A: DFT over w ----------------
    {
        unsigned short* xbf = (unsigned short*)smem;   // 16 KB [w][c]
        #pragma unroll 1
        for (int u = 0; u < 4; ++u) {
            int bh = blk * 4 + u;
            __syncthreads();
            const float* xp = x + (size_t)bh * (WW * CC);
            for (int i = tid * 4; i < WW * CC; i += 1024) {
                float4 v = *(const float4*)&xp[i];
                *(ushort4*)&xbf[i] = make_ushort4(f2bf(v.x), f2bf(v.y), f2bf(v.z), f2bf(v.w));
            }
            __syncthreads();
            int nt = wid;
            bf16x8 bfv[4];
            #pragma unroll
            for (int ks = 0; ks < 4; ++ks) {
                short v[8];
                #pragma unroll
                for (int e = 0; e < 8; ++e)
                    v[e] = (short)xbf[(ks * 32 + q * 8 + e) * CC + nt * 16 + r];
                bfv[ks] = *(const bf16x8*)v;
            }
            f32x4 acc0 = {0.f, 0.f, 0.f, 0.f}, acc1 = {0.f, 0.f, 0.f, 0.f};
            #pragma unroll
            for (int ks = 0; ks < 4; ++ks) {
                bf16x8 a0 = *(const bf16x8*)&FR[((size_t)((0 * 4 + ks) * 64 + lane)) * 8];
                bf16x8 a1 = *(const bf16x8*)&FR[((size_t)((1 * 4 + ks) * 64 + lane)) * 8];
                acc0 = __builtin_amdgcn_mfma_f32_16x16x32_bf16(a0, bfv[ks], acc0, 0, 0, 0);
                acc1 = __builtin_amdgcn_mfma_f32_16x16x32_bf16(a1, bfv[ks], acc1, 0, 0, 0);
            }
            __syncthreads();
            unsigned short* asT = xbf;                // [32 m][64 c]
            int c = nt * 16 + r;
            #pragma unroll
            for (int j = 0; j < 4; ++j) {
                int m0 = q * 4 + j;
                asT[m0 * 64 + c] = f2bf(acc0[j]);
                asT[(16 + m0) * 64 + c] = f2bf(acc1[j]);
            }
            __syncthreads();
            int b = bh >> 7, h = bh & 127;
            int ky = tid >> 4, idx8 = tid & 15;
            int ri = idx8 >> 3, c0 = (idx8 & 7) * 8;
            bf16x8 vv = *(const bf16x8*)&asT[(2 * ky + ri) * 64 + c0];
            *(bf16x8*)&X1[(((size_t)b * 16 + ky) * 128 + h) * 128 + ri * 64 + c0] = vv;
        }
    }
    __threadfence();
    grid.sync();

    // ---------------- Stage B: DFT over h (512 active blocks) ----------------
    if (blk < 512) {
        unsigned short* xb = (unsigned short*)smem;   // 32 KB [k=2h+ri][c]
        int b = blk >> 4, ky = blk & 15;
        const unsigned short* p = X1 + ((size_t)b * 16 + ky) * 16384;
        for (int i = tid * 8; i < 256 * 64; i += 2048)
            *(bf16x8*)&xb[i] = *(const bf16x8*)&p[i];
        __syncthreads();
        const unsigned short* FB = FR + 4096;         // slot 512
        int col = wid * 16 + r;
        bf16x8 bfv[8];
        #pragma unroll
        for (int ks = 0; ks < 8; ++ks) {
            short v[8];
            #pragma unroll
            for (int e = 0; e < 8; ++e)
                v[e] = (short)xb[(ks * 32 + q * 8 + e) * 64 + col];
            bfv[ks] = *(const bf16x8*)v;
        }
        f32x4 acc[4] = {{0.f,0.f,0.f,0.f},{0.f,0.f,0.f,0.f},{0.f,0.f,0.f,0.f},{0.f,0.f,0.f,0.f}};
        #pragma unroll
        for (int ks = 0; ks < 8; ++ks) {
            #pragma unroll
            for (int mt = 0; mt < 4; ++mt) {
                bf16x8 a = *(const bf16x8*)&FB[((size_t)((mt * 8 + ks) * 64 + lane)) * 8];
                acc[mt] = __builtin_amdgcn_mfma_f32_16x16x32_bf16(a, bfv[ks], acc[mt], 0, 0, 0);
            }
        }
        __syncthreads();
        unsigned short* asT = xb;                     // [64 m=2kxi+rr][64 c]
        #pragma unroll
        for (int mt = 0; mt < 4; ++mt)
            #pragma unroll
            for (int j = 0; j < 4; ++j)
                asT[(mt * 16 + q * 4 + j) * 64 + col] = f2bf(acc[mt][j]);
        __syncthreads();
        int kxi = tid >> 3, part = tid & 7;
        short v2[16];
        #pragma unroll
        for (int s = 0; s < 16; ++s) {
            int n = part * 16 + s, cc2 = n >> 1, rr = n & 1;
            v2[s] = (short)asT[(2 * kxi + rr) * 64 + cc2];
        }
        unsigned short* dst = &X2[(((size_t)b * NKX + kxi) * 16 + ky) * 128 + part * 16];
        *(bf16x8*)&dst[0] = *(const bf16x8*)&v2[0];
        *(bf16x8*)&dst[8] = *(const bf16x8*)&v2[8];
    }
    __threadfence();
    grid.sync();

    // ---------------- Stage C: channel mix (512 active blocks) ----------------
    if (blk < 512) {
        unsigned short* wbr = (unsigned short*)smem;  // 8 KB [i][o]
        unsigned short* wbi = wbr + CC * CC;          // 8 KB
        unsigned short* asT = wbi + CC * CC;          // 8 KB [32 b][128 n]
        int kxi = blk >> 4, ky = blk & 15;
        const float* wr = (kxi < 16) ? w1r : w2r;
        const float* wi = (kxi < 16) ? w1i : w2i;
        int wx = (kxi < 16) ? kxi : (kxi - 16);
        size_t woff = ((size_t)wx * MY + ky) * (CC * CC);
        for (int i = tid * 4; i < CC * CC; i += 1024) {
            float4 a = *(const float4*)&wr[woff + i];
            float4 bq = *(const float4*)&wi[woff + i];
            *(ushort4*)&wbr[i] = make_ushort4(f2bf(a.x), f2bf(a.y), f2bf(a.z), f2bf(a.w));
            *(ushort4*)&wbi[i] = make_ushort4(f2bf(bq.x), f2bf(bq.y), f2bf(bq.z), f2bf(bq.w));
        }
        __syncthreads();
        bf16x8 af[2][4];
        #pragma unroll
        for (int mt = 0; mt < 2; ++mt) {
            int b = mt * 16 + r;
            #pragma unroll
            for (int ks = 0; ks < 4; ++ks)
                af[mt][ks] = *(const bf16x8*)&X2[(((size_t)b * NKX + kxi) * 16 + ky) * 128 + ks * 32 + q * 8];
        }
        bf16x8 bfr[2][4];
        #pragma unroll
        for (int t = 0; t < 2; ++t) {
            int n = (wid * 2 + t) * 16 + r;
            int o = n >> 1, ro = n & 1;
            #pragma unroll
            for (int ks = 0; ks < 4; ++ks) {
                short v[8];
                #pragma unroll
                for (int e = 0; e < 8; ++e) {
                    int k = ks * 32 + q * 8 + e;
                    int i = k >> 1, ri = k & 1;
                    unsigned short raw = (ri == 0) ? (ro ? wbi[i * 64 + o] : wbr[i * 64 + o])
                                                   : (ro ? wbr[i * 64 + o] : (unsigned short)(wbi[i * 64 + o] ^ 0x8000u));
                    v[e] = (short)raw;
                }
                bfr[t][ks] = *(const bf16x8*)v;
            }
        }
        f32x4 acc[2][2] = {{{0.f,0.f,0.f,0.f},{0.f,0.f,0.f,0.f}},{{0.f,0.f,0.f,0.f},{0.f,0.f,0.f,0.f}}};
        #pragma unroll
        for (int ks = 0; ks < 4; ++ks)
            #pragma unroll
            for (int mt = 0; mt < 2; ++mt)
                #pragma unroll
                for (int t = 0; t < 2; ++t)
                    acc[mt][t] = __builtin_amdgcn_mfma_f32_16x16x32_bf16(af[mt][ks], bfr[t][ks], acc[mt][t], 0, 0, 0);
        #pragma unroll
        for (int mt = 0; mt < 2; ++mt)
            #pragma unroll
            for (int t = 0; t < 2; ++t)
                #pragma unroll
                for (int j = 0; j < 4; ++j)
                    asT[(mt * 16 + q * 4 + j) * 128 + (wid * 2 + t) * 16 + r] = f2bf(acc[mt][t][j]);
        __syncthreads();
        int bb = tid >> 3, part = tid & 7;
        bf16x8 u0 = *(const bf16x8*)&asT[bb * 128 + part * 16];
        bf16x8 u1 = *(const bf16x8*)&asT[bb * 128 + part * 16 + 8];
        unsigned short* dst = &G[(((size_t)bb * NKX + kxi) * 16 + ky) * 128 + part * 16];
        *(bf16x8*)&dst[0] = u0;
        *(bf16x8*)&dst[8] = u1;
    }
    __threadfence();
    grid.sync();

    // ---------------- Stage D: inverse DFT over kx (1024 blocks) ----------------
    {
        unsigned short* gs = (unsigned short*)smem;   // 8 KB
        int b = blk >> 5, ky = (blk >> 1) & 15, mh = blk & 1;
        __syncthreads();
        for (int i = tid * 8; i < NKX * 128; i += 2048) {
            int kxi = i >> 7, n = i & 127;
            *(bf16x8*)&gs[i] = *(const bf16x8*)&G[(((size_t)b * NKX + kxi) * 16 + ky) * 128 + n];
        }
        __syncthreads();
        const unsigned short* FD = FR + 20480;        // slot 2560
        bf16x8 bfr[2][2];
        #pragma unroll
        for (int t = 0; t < 2; ++t) {
            int n = (wid * 2 + t) * 16 + r;
            #pragma unroll
            for (int ks = 0; ks < 2; ++ks) {
                short v[8];
                #pragma unroll
                for (int e = 0; e < 8; ++e) {
                    int k = ks * 32 + q * 8 + e;
                    int kxi = k >> 1, ri = k & 1;
                    unsigned short raw = gs[kxi * 128 + (n ^ ri)];
                    if (ri & (n & 1)) raw ^= 0x8000u;
                    v[e] = (short)raw;
                }
                bfr[t][ks] = *(const bf16x8*)v;
            }
        }
        #pragma unroll
        for (int mt2 = 0; mt2 < 4; ++mt2) {
            int mt = mh * 4 + mt2;
            f32x4 acc[2] = {{0.f,0.f,0.f,0.f},{0.f,0.f,0.f,0.f}};
            #pragma unroll
            for (int ks = 0; ks < 2; ++ks) {
                bf16x8 a = *(const bf16x8*)&FD[((size_t)((mt * 2 + ks) * 64 + lane)) * 8];
                #pragma unroll
                for (int t = 0; t < 2; ++t)
                    acc[t] = __builtin_amdgcn_mfma_f32_16x16x32_bf16(a, bfr[t][ks], acc[t], 0, 0, 0);
            }
            #pragma unroll
            for (int t = 0; t < 2; ++t)
                #pragma unroll
                for (int j = 0; j < 4; ++j) {
                    int h = mt * 16 + q * 4 + j;
                    int n = (wid * 2 + t) * 16 + r;
                    int c = n >> 1, reim = n & 1;
                    int kp = 2 * ky + reim, q2 = kp >> 3, e2 = kp & 7;
                    int nt2 = c >> 4, r2 = c & 15;
                    Zf[(((size_t)b * 128 + h) * 4 + nt2) * 512 + (q2 * 16 + r2) * 8 + e2] = f2bf(acc[t][j]);
                }
        }
    }
    __threadfence();
    grid.sync();

    // ---------------- Stage E: inverse-ky + dense + residual + GELU ----------------
    {
        float* xs = (float*)smem;                     // 128*68*4 = 34,816 B
        const unsigned short* FEAT = FR + 28672;      // slot 3584
        const unsigned short* FEBK = FR + 32768;      // slot 4096
        #pragma unroll 1
        for (int u = 0; u < 4; ++u) {
            int bh = blk * 4 + u;
            __syncthreads();
            const float* xp = x + (size_t)bh * (WW * CC);
            for (int i = tid * 4; i < WW * CC; i += 1024) {
                int w = i >> 6, c = i & 63;
                *(float4*)&xs[w * 68 + c] = *(const float4*)&xp[i];
            }
            __syncthreads();
            bf16x8 ax[2][2], at[2];
            #pragma unroll
            for (int t2 = 0; t2 < 2; ++t2) {
                int tm = wid * 2 + t2;
                int row = tm * 16 + r;
                #pragma unroll
                for (int ks = 0; ks < 2; ++ks) {
                    const float* s = &xs[row * 68 + ks * 32 + q * 8];
                    short v[8];
                    #pragma unroll
                    for (int e = 0; e < 8; ++e) v[e] = (short)f2bf(s[e]);
                    ax[t2][ks] = *(const bf16x8*)v;
                }
                at[t2] = *(const bf16x8*)&FEAT[((size_t)(tm * 64 + lane)) * 8];
            }
            #pragma unroll
            for (int nt = 0; nt < 4; ++nt) {
                bf16x8 b0 = *(const bf16x8*)&FEBK[((size_t)((nt * 2 + 0) * 64 + lane)) * 8];
                bf16x8 b1 = *(const bf16x8*)&FEBK[((size_t)((nt * 2 + 1) * 64 + lane)) * 8];
                bf16x8 bz = *(const bf16x8*)&Zf[((size_t)bh * 4 + nt) * 512 + lane * 8];
                int c = nt * 16 + r;
                float bsv = bias[c];
                #pragma unroll
                for (int t2 = 0; t2 < 2; ++t2) {
                    int tm = wid * 2 + t2;
                    f32x4 acc = {0.f, 0.f, 0.f, 0.f};
                    acc = __builtin_amdgcn_mfma_f32_16x16x32_bf16(ax[t2][0], b0, acc, 0, 0, 0);
                    acc = __builtin_amdgcn_mfma_f32_16x16x32_bf16(ax[t2][1], b1, acc, 0, 0, 0);
                    acc = __builtin_amdgcn_mfma_f32_16x16x32_bf16(at[t2], bz, acc, 0, 0, 0);
                    #pragma unroll
                    for (int j = 0; j < 4; ++j) {
                        int w = tm * 16 + q * 4 + j;
                        float uu = acc[j] + xs[w * 68 + c] + bsv;
                        float t = uu + 0.044715f * uu * uu * uu;
                        float e = __expf(-1.5957691216057308f * t);
                        out[(size_t)bh * (WW * CC) + w * CC + c] = uu / (1.0f + e);
                    }
                }
            }
        }
    }
}

// ======================= fallback standalone kernels (round-5) =======================
__global__ __launch_bounds__(256) void kA(const float* __restrict__ x, const unsigned short* __restrict__ FR,
                                          unsigned short* __restrict__ X1) {
    __shared__ unsigned short xbf[WW * CC];
    int tid = threadIdx.x, bh = blockIdx.x;
    const float* xp = x + (size_t)bh * (WW * CC);
    for (int i = tid * 4; i < WW * CC; i += 1024) {
        float4 v = *(const float4*)&xp[i];
        *(ushort4*)&xbf[i] = make_ushort4(f2bf(v.x), f2bf(v.y), f2bf(v.z), f2bf(v.w));
    }
    __syncthreads();
    int lane = tid & 63, nt = tid >> 6, q = lane >> 4, r = lane & 15;
    bf16x8 bfv[4];
    #pragma unroll
    for (int ks = 0; ks < 4; ++ks) {
        short v[8];
        #pragma unroll
        for (int e = 0; e < 8; ++e)
            v[e] = (short)xbf[(ks * 32 + q * 8 + e) * CC + nt * 16 + r];
        bfv[ks] = *(const bf16x8*)v;
    }
    f32x4 acc0 = {0.f, 0.f, 0.f, 0.f}, acc1 = {0.f, 0.f, 0.f, 0.f};
    #pragma unroll
    for (int ks = 0; ks < 4; ++ks) {
        bf16x8 a0 = *(const bf16x8*)&FR[((size_t)((0 * 4 + ks) * 64 + lane)) * 8];
        bf16x8 a1 = *(const bf16x8*)&FR[((size_t)((1 * 4 + ks) * 64 + lane)) * 8];
        acc0 = __builtin_amdgcn_mfma_f32_16x16x32_bf16(a0, bfv[ks], acc0, 0, 0, 0);
        acc1 = __builtin_amdgcn_mfma_f32_16x16x32_bf16(a1, bfv[ks], acc1, 0, 0, 0);
    }
    __syncthreads();
    unsigned short* asT = xbf;
    int c = nt * 16 + r;
    #pragma unroll
    for (int j = 0; j < 4; ++j) {
        int m0 = q * 4 + j;
        asT[m0 * 64 + c] = f2bf(acc0[j]);
        asT[(16 + m0) * 64 + c] = f2bf(acc1[j]);
    }
    __syncthreads();
    int b = bh >> 7, h = bh & 127;
    int ky = tid >> 4, idx8 = tid & 15;
    int ri = idx8 >> 3, c0 = (idx8 & 7) * 8;
    bf16x8 vv = *(const bf16x8*)&asT[(2 * ky + ri) * 64 + c0];
    *(bf16x8*)&X1[(((size_t)b * 16 + ky) * 128 + h) * 128 + ri * 64 + c0] = vv;
}

__global__ __launch_bounds__(256) void kB(const unsigned short* __restrict__ X1, const unsigned short* __restrict__ FR,
                                          unsigned short* __restrict__ X2) {
    __shared__ unsigned short xb[256 * 64];
    int tid = threadIdx.x, blk = blockIdx.x;
    int b = blk >> 4, ky = blk & 15;
    const unsigned short* p = X1 + ((size_t)b * 16 + ky) * 16384;
    for (int i = tid * 8; i < 256 * 64; i += 2048)
        *(bf16x8*)&xb[i] = *(const bf16x8*)&p[i];
    __syncthreads();
    const unsigned short* FB = FR + 4096;
    int lane = tid & 63, wid = tid >> 6, q = lane >> 4, r = lane & 15;
    int col = wid * 16 + r;
    bf16x8 bfv[8];
    #pragma unroll
    for (int ks = 0; ks < 8; ++ks) {
        short v[8];
        #pragma unroll
        for (int e = 0; e < 8; ++e)
            v[e] = (short)xb[(ks * 32 + q * 8 + e) * 64 + col];
        bfv[ks] = *(const bf16x8*)v;
    }
    f32x4 acc[4] = {{0.f,0.f,0.f,0.f},{0.f,0.f,0.f,0.f},{0.f,0.f,0.f,0.f},{0.f,0.f,0.f,0.f}};
    #pragma unroll
    for (int ks = 0; ks < 8; ++ks) {
        #pragma unroll
        for (int mt = 0; mt < 4; ++mt) {
            bf16x8 a = *(const bf16x8*)&FB[((size_t)((mt * 8 + ks) * 64 + lane)) * 8];
            acc[mt] = __builtin_amdgcn_mfma_f32_16x16x32_bf16(a, bfv[ks], acc[mt], 0, 0, 0);
        }
    }
    __syncthreads();
    unsigned short* asT = xb;
    #pragma unroll
    for (int mt = 0; mt < 4; ++mt)
        #pragma unroll
        for (int j = 0; j < 4; ++j)
            asT[(mt * 16 + q * 4 + j) * 64 + col] = f2bf(acc[mt][j]);
    __syncthreads();
    int kxi = tid >> 3, part = tid & 7;
    short v2[16];
    #pragma unroll
    for (int s = 0; s < 16; ++s) {
        int n = part * 16 + s, cc2 = n >> 1, rr = n & 1;
        v2[s] = (short)asT[(2 * kxi + rr) * 64 + cc2];
    }
    unsigned short* dst = &X2[(((size_t)b * NKX + kxi) * 16 + ky) * 128 + part * 16];
    *(bf16x8*)&dst[0] = *(const bf16x8*)&v2[0];
    *(bf16x8*)&dst[8] = *(const bf16x8*)&v2[8];
}

__global__ __launch_bounds__(256) void kC(const float* __restrict__ w1r, const float* __restrict__ w1i,
                                          const float* __restrict__ w2r, const float* __restrict__ w2i,
                                          const unsigned short* __restrict__ X2, unsigned short* __restrict__ G) {
    __shared__ unsigned short wbr[CC * CC];
    __shared__ unsigned short wbi[CC * CC];
    __shared__ unsigned short asT[32 * 128];
    int tid = threadIdx.x;
    int blk = blockIdx.x;
    int kxi = blk >> 4, ky = blk & 15;
    const float* wr = (kxi < 16) ? w1r : w2r;
    const float* wi = (kxi < 16) ? w1i : w2i;
    int wx = (kxi < 16) ? kxi : (kxi - 16);
    size_t woff = ((size_t)wx * MY + ky) * (CC * CC);
    for (int i = tid * 4; i < CC * CC; i += 1024) {
        float4 a = *(const float4*)&wr[woff + i];
        float4 bq = *(const float4*)&wi[woff + i];
        *(ushort4*)&wbr[i] = make_ushort4(f2bf(a.x), f2bf(a.y), f2bf(a.z), f2bf(a.w));
        *(ushort4*)&wbi[i] = make_ushort4(f2bf(bq.x), f2bf(bq.y), f2bf(bq.z), f2bf(bq.w));
    }
    __syncthreads();
    int lane = tid & 63, wid = tid >> 6;
    int q = lane >> 4, r = lane & 15;
    bf16x8 af[2][4];
    #pragma unroll
    for (int mt = 0; mt < 2; ++mt) {
        int b = mt * 16 + r;
        #pragma unroll
        for (int ks = 0; ks < 4; ++ks)
            af[mt][ks] = *(const bf16x8*)&X2[(((size_t)b * NKX + kxi) * 16 + ky) * 128 + ks * 32 + q * 8];
    }
    bf16x8 bfr[2][4];
    #pragma unroll
    for (int t = 0; t < 2; ++t) {
        int n = (wid * 2 + t) * 16 + r;
        int o = n >> 1, ro = n & 1;
        #pragma unroll
        for (int ks = 0; ks < 4; ++ks) {
            short v[8];
            #pragma unroll
            for (int e = 0; e < 8; ++e) {
                int k = ks * 32 + q * 8 + e;
                int i = k >> 1, ri = k & 1;
                unsigned short raw = (ri == 0) ? (ro ? wbi[i * 64 + o] : wbr[i * 64 + o])
                                               : (ro ? wbr[i * 64 + o] : (unsigned short)(wbi[i * 64 + o] ^ 0x8000u));
                v[e] = (short)raw;
            }
            bfr[t][ks] = *(const bf16x8*)v;
        }
    }
    f32x4 acc[2][2] = {{{0.f,0.f,0.f,0.f},{0.f,0.f,0.f,0.f}},{{0.f,0.f,0.f,0.f},{0.f,0.f,0.f,0.f}}};
    #pragma unroll
    for (int ks = 0; ks < 4; ++ks)
        #pragma unroll
        for (int mt = 0; mt < 2; ++mt)
            #pragma unroll
            for (int t = 0; t < 2; ++t)
                acc[mt][t] = __builtin_amdgcn_mfma_f32_16x16x32_bf16(af[mt][ks], bfr[t][ks], acc[mt][t], 0, 0, 0);
    #pragma unroll
    for (int mt = 0; mt < 2; ++mt)
        #pragma unroll
        for (int t = 0; t < 2; ++t)
            #pragma unroll
            for (int j = 0; j < 4; ++j)
                asT[(mt * 16 + q * 4 + j) * 128 + (wid * 2 + t) * 16 + r] = f2bf(acc[mt][t][j]);
    __syncthreads();
    int bb = tid >> 3, part = tid & 7;
    bf16x8 u0 = *(const bf16x8*)&asT[bb * 128 + part * 16];
    bf16x8 u1 = *(const bf16x8*)&asT[bb * 128 + part * 16 + 8];
    unsigned short* dst = &G[(((size_t)bb * NKX + kxi) * 16 + ky) * 128 + part * 16];
    *(bf16x8*)&dst[0] = u0;
    *(bf16x8*)&dst[8] = u1;
}

__global__ __launch_bounds__(256) void kD(const unsigned short* __restrict__ G, const unsigned short* __restrict__ FR,
                                          unsigned short* __restrict__ Zf) {
    __shared__ unsigned short gs[NKX * 128];
    int tid = threadIdx.x, blk = blockIdx.x;
    int b = blk >> 5, ky = (blk >> 1) & 15, mh = blk & 1;
    for (int i = tid * 8; i < NKX * 128; i += 2048) {
        int kxi = i >> 7, n = i & 127;
        *(bf16x8*)&gs[i] = *(const bf16x8*)&G[(((size_t)b * NKX + kxi) * 16 + ky) * 128 + n];
    }
    __syncthreads();
    int lane = tid & 63, wid = tid >> 6, q = lane >> 4, r = lane & 15;
    const unsigned short* FD = FR + 20480;
    bf16x8 bfr[2][2];
    #pragma unroll
    for (int t = 0; t < 2; ++t) {
        int n = (wid * 2 + t) * 16 + r;
        #pragma unroll
        for (int ks = 0; ks < 2; ++ks) {
            short v[8];
            #pragma unroll
            for (int e = 0; e < 8; ++e) {
                int k = ks * 32 + q * 8 + e;
                int kxi = k >> 1, ri = k & 1;
                unsigned short raw = gs[kxi * 128 + (n ^ ri)];
                if (ri & (n & 1)) raw ^= 0x8000u;
                v[e] = (short)raw;
            }
            bfr[t][ks] = *(const bf16x8*)v;
        }
    }
    #pragma unroll
    for (int mt2 = 0; mt2 < 4; ++mt2) {
        int mt = mh * 4 + mt2;
        f32x4 acc[2] = {{0.f,0.f,0.f,0.f},{0.f,0.f,0.f,0.f}};
        #pragma unroll
        for (int ks = 0; ks < 2; ++ks) {
            bf16x8 a = *(const bf16x8*)&FD[((size_t)((mt * 2 + ks) * 64 + lane)) * 8];
            #pragma unroll
            for (int t = 0; t < 2; ++t)
                acc[t] = __builtin_amdgcn_mfma_f32_16x16x32_bf16(a, bfr[t][ks], acc[t], 0, 0, 0);
        }
        #pragma unroll
        for (int t = 0; t < 2; ++t)
            #pragma unroll
            for (int j = 0; j < 4; ++j) {
                int h = mt * 16 + q * 4 + j;
                int n = (wid * 2 + t) * 16 + r;
                int c = n >> 1, reim = n & 1;
                int kp = 2 * ky + reim, q2 = kp >> 3, e2 = kp & 7;
                int nt2 = c >> 4, r2 = c & 15;
                Zf[(((size_t)b * 128 + h) * 4 + nt2) * 512 + (q2 * 16 + r2) * 8 + e2] = f2bf(acc[t][j]);
            }
    }
}

__global__ __launch_bounds__(256) void kE(const float* __restrict__ x, const unsigned short* __restrict__ Zf,
                                          const unsigned short* __restrict__ FR,
                                          const float* __restrict__ bias, float* __restrict__ out) {
    __shared__ float xs[WW * 68];
    int tid = threadIdx.x, bh = blockIdx.x;
    const float* xp = x + (size_t)bh * (WW * CC);
    for (int i = tid * 4; i < WW * CC; i += 1024) {
        int w = i >> 6, c = i & 63;
        *(float4*)&xs[w * 68 + c] = *(const float4*)&xp[i];
    }
    __syncthreads();
    int lane = tid & 63, wv = tid >> 6, q = lane >> 4, r = lane & 15;
    const unsigned short* FEAT = FR + 28672;
    const unsigned short* FEBK = FR + 32768;
    bf16x8 ax[2][2], at[2];
    #pragma unroll
    for (int t2 = 0; t2 < 2; ++t2) {
        int tm = wv * 2 + t2;
        int row = tm * 16 + r;
        #pragma unroll
        for (int ks = 0; ks < 2; ++ks) {
            const float* s = &xs[row * 68 + ks * 32 + q * 8];
            short v[8];
            #pragma unroll
            for (int e = 0; e < 8; ++e) v[e] = (short)f2bf(s[e]);
            ax[t2][ks] = *(const bf16x8*)v;
        }
        at[t2] = *(const bf16x8*)&FEAT[((size_t)(tm * 64 + lane)) * 8];
    }
    #pragma unroll
    for (int nt = 0; nt < 4; ++nt) {
        bf16x8 b0 = *(const bf16x8*)&FEBK[((size_t)((nt * 2 + 0) * 64 + lane)) * 8];
        bf16x8 b1 = *(const bf16x8*)&FEBK[((size_t)((nt * 2 + 1) * 64 + lane)) * 8];
        bf16x8 bz = *(const bf16x8*)&Zf[((size_t)bh * 4 + nt) * 512 + lane * 8];
        int c = nt * 16 + r;
        float bsv = bias[c];
        #pragma unroll
        for (int t2 = 0; t2 < 2; ++t2) {
            int tm = wv * 2 + t2;
            f32x4 acc = {0.f, 0.f, 0.f, 0.f};
            acc = __builtin_amdgcn_mfma_f32_16x16x32_bf16(ax[t2][0], b0, acc, 0, 0, 0);
            acc = __builtin_amdgcn_mfma_f32_16x16x32_bf16(ax[t2][1], b1, acc, 0, 0, 0);
            acc = __builtin_amdgcn_mfma_f32_16x16x32_bf16(at[t2], bz, acc, 0, 0, 0);
            #pragma unroll
            for (int j = 0; j < 4; ++j) {
                int w = tm * 16 + q * 4 + j;
                float u = acc[j] + xs[w * 68 + c] + bsv;
                float t = u + 0.044715f * u * u * u;
                float e = __expf(-1.5957691216057308f * t);
                out[(size_t)bh * (WW * CC) + w * CC + c] = u / (1.0f + e);
            }
        }
    }
}

extern "C" void kernel_launch(void* const* d_in, const int* in_sizes, int n_in,
                              void* d_out, int out_size, void* d_ws, size_t ws_size,
                              hipStream_t stream) {
    const float* x   = (const float*)d_in[0];
    const float* w1r = (const float*)d_in[1];
    const float* w1i = (const float*)d_in[2];
    const float* w2r = (const float*)d_in[3];
    const float* w2i = (const float*)d_in[4];
    const float* dk  = (const float*)d_in[5];
    const float* db  = (const float*)d_in[6];
    float* out = (float*)d_out;

    unsigned short* FR = (unsigned short*)d_ws;      // 4608*8 shorts, padded to 128 KB
    unsigned short* X1 = FR + 65536;                 // 8,388,608 elems
    unsigned short* X2 = X1 + 8388608;               // 2,097,152 elems
    unsigned short* G  = X2 + 2097152;               // 2,097,152 elems
    unsigned short* Zf = G  + 2097152;               // 8,388,608 elems

    kT<<<18, 256, 0, stream>>>(dk, FR);

    const float* xa = x; const float* a1 = w1r; const float* a2 = w1i;
    const float* a3 = w2r; const float* a4 = w2i; const float* bb = db;
    const unsigned short* fr = FR;
    unsigned short* x1 = X1; unsigned short* x2 = X2;
    unsigned short* gg = G; unsigned short* zf = Zf;
    float* oo = out;
    void* args[] = {(void*)&xa, (void*)&a1, (void*)&a2, (void*)&a3, (void*)&a4,
                    (void*)&bb, (void*)&fr, (void*)&x1, (void*)&x2, (void*)&gg,
                    (void*)&zf, (void*)&oo};
    hipError_t err = hipLaunchCooperativeKernel((const void*)kFused, dim3(1024), dim3(256),
                                                args, 0, stream);
    if (err != hipSuccess) {
        // fallback: serialized multi-kernel pipeline (round-5 verified path)
        kA<<<BB * HH, 256, 0, stream>>>(x, FR, X1);
        kB<<<BB * MY, 256, 0, stream>>>(X1, FR, X2);
        kC<<<NKX * MY, 256, 0, stream>>>(w1r, w1i, w2r, w2i, X2, G);
        kD<<<BB * MY * 2, 256, 0, stream>>>(G, FR, Zf);
        kE<<<BB * HH, 256, 0, stream>>>(x, Zf, FR, db, out);
    }
}

// Round 7
// 323.302 us; speedup vs baseline: 4.0256x; 4.0256x over previous
//
#include <hip/hip_runtime.h>
#include <math.h>

#define BB 32
#define HH 128
#define WW 128
#define CC 64
#define MX 16
#define MY 16
#define NKX 32   // kx modes: 0..15 and 112..127

#define TWOPI 6.283185307179586f

typedef __attribute__((ext_vector_type(8))) short bf16x8;
typedef __attribute__((ext_vector_type(4))) float f32x4;

__device__ inline unsigned short f2bf(float f) {
    union { float f; unsigned u; } v; v.f = f;
    unsigned r = v.u + 0x7FFFu + ((v.u >> 16) & 1u);   // RTNE
    return (unsigned short)(r >> 16);
}
__device__ inline float bf2f(unsigned short u) {
    union { unsigned u; float f; } v; v.u = ((unsigned)u) << 16; return v.f;
}

// ws layout (shorts):
//   FR  [4608 slots][8] : precomputed bf16 fragments (FA/FB/FD/FEAT/FEBK), padded to 128 KB
//   X1  [32][16][128][2][64]   X2 [32][32][16][128]   G [32][32][16][128]
//   Zf  [32][128][4][512]  (kE B-frag layout)
//   Xbf [32*128][128][64]  bf16 copy of x (written by kA, read by kE)
// Fragment convention (verified rounds 2-6):
//   A-frag: lane l=(q=l>>4, r=l&15) holds A[row=r][k=q*8+e]
//   B-frag: lane l holds B[k=q*8+e][col=r]
//   C/D   : acc[j] -> row=q*4+j, col=r

// ---------------- kT: build all block-invariant fragments ----------------
__global__ __launch_bounds__(256) void kT(const float* __restrict__ K, unsigned short* __restrict__ FR) {
    __shared__ float2 tw[128];
    int tid = threadIdx.x;
    if (tid < 128) {
        float s, c;
        sincosf(TWOPI * (float)tid * (1.0f / 128.0f), &s, &c);
        tw[tid] = make_float2(c, s);
    }
    __syncthreads();
    int g = blockIdx.x * 256 + tid;       // 0..4607
    short v[8];
    if (g < 512) {                        // FA: A[row=2ky+ri][w]
        int s = g;
        int l = s & 63, ks = (s >> 6) & 3, mt = s >> 8;
        int q = l >> 4, r = l & 15;
        int row = mt * 16 + r, ky = row >> 1, ri = row & 1;
        int k0 = ks * 32 + q * 8;
        #pragma unroll
        for (int e = 0; e < 8; ++e) {
            float2 t = tw[(ky * (k0 + e)) & 127];
            v[e] = (short)f2bf(ri ? -t.y : t.x);
        }
    } else if (g < 2560) {                // FB: A[row=2kxi+rr][k=2h+ri]
        int s = g - 512;
        int l = s & 63, ks = (s >> 6) & 7, mt = s >> 9;
        int q = l >> 4, r = l & 15;
        int row = mt * 16 + r, kxi = row >> 1, rr = row & 1;
        int kx = (kxi < 16) ? kxi : (96 + kxi);
        int k0 = ks * 32 + q * 8;
        #pragma unroll
        for (int e = 0; e < 8; ++e) {
            int k = k0 + e, h = k >> 1, ri = k & 1;
            float2 t = tw[(kx * h) & 127];
            float val = (rr == 0) ? (ri == 0 ? t.x : t.y) : (ri == 0 ? -t.y : t.x);
            v[e] = (short)f2bf(val);
        }
    } else if (g < 3584) {                // FD: A[row=h][k=2kxi+ri]
        int s = g - 2560;
        int l = s & 63, ks = (s >> 6) & 1, mt = s >> 7;
        int q = l >> 4, r = l & 15;
        int h = mt * 16 + r;
        int k0 = ks * 32 + q * 8;
        #pragma unroll
        for (int e = 0; e < 8; ++e) {
            int k = k0 + e, kxi = k >> 1, ri = k & 1;
            int kx = (kxi < 16) ? kxi : (96 + kxi);
            float2 t = tw[(kx * h) & 127];
            v[e] = (short)f2bf(ri == 0 ? t.x : -t.y);
        }
    } else if (g < 4096) {                // FEAT: kE A ks=2 (inverse-ky twiddles, scaled)
        int s = g - 3584;
        int l = s & 63, tm = s >> 6;
        int q = l >> 4, r = l & 15;
        int row = tm * 16 + r;
        const float inv = 1.0f / 16384.0f;
        #pragma unroll
        for (int e = 0; e < 8; ++e) {
            int ky = 4 * q + (e >> 1);
            float sc = ((ky == 0) ? 1.0f : 2.0f) * inv;
            float2 t = tw[(ky * row) & 127];
            v[e] = (short)f2bf((e & 1) ? (-t.y * sc) : (t.x * sc));
        }
    } else {                              // FEBK: kE B ks=0,1 (dense kernel K)
        int s = g - 4096;
        int l = s & 63, ks = (s >> 6) & 1, nt = s >> 7;
        int q = l >> 4, r = l & 15;
        int col = nt * 16 + r;
        #pragma unroll
        for (int e = 0; e < 8; ++e) {
            int k = ks * 32 + q * 8 + e;
            v[e] = (short)f2bf(K[k * CC + col]);
        }
    }
    *(bf16x8*)&FR[(size_t)g * 8] = *(const bf16x8*)v;
}

// ---------------- kA: DFT over w as GEMM; also emits Xbf (bf16 copy of x) ----------------
__global__ __launch_bounds__(256) void kA(const float* __restrict__ x, const unsigned short* __restrict__ FR,
                                          unsigned short* __restrict__ X1, unsigned short* __restrict__ Xbf) {
    __shared__ unsigned short xbf[WW * CC];   // 16 KB [w][c]
    int tid = threadIdx.x, bh = blockIdx.x;
    const float* xp = x + (size_t)bh * (WW * CC);
    unsigned short* xbp = Xbf + (size_t)bh * (WW * CC);
    for (int i = tid * 4; i < WW * CC; i += 1024) {
        float4 v = *(const float4*)&xp[i];
        ushort4 pk = make_ushort4(f2bf(v.x), f2bf(v.y), f2bf(v.z), f2bf(v.w));
        *(ushort4*)&xbf[i] = pk;
        *(ushort4*)&xbp[i] = pk;              // persist bf16 x for kE
    }
    __syncthreads();
    int lane = tid & 63, nt = tid >> 6, q = lane >> 4, r = lane & 15;
    bf16x8 bfv[4];
    #pragma unroll
    for (int ks = 0; ks < 4; ++ks) {
        short v[8];
        #pragma unroll
        for (int e = 0; e < 8; ++e)
            v[e] = (short)xbf[(ks * 32 + q * 8 + e) * CC + nt * 16 + r];
        bfv[ks] = *(const bf16x8*)v;
    }
    f32x4 acc0 = {0.f, 0.f, 0.f, 0.f}, acc1 = {0.f, 0.f, 0.f, 0.f};
    #pragma unroll
    for (int ks = 0; ks < 4; ++ks) {
        bf16x8 a0 = *(const bf16x8*)&FR[((size_t)((0 * 4 + ks) * 64 + lane)) * 8];
        bf16x8 a1 = *(const bf16x8*)&FR[((size_t)((1 * 4 + ks) * 64 + lane)) * 8];
        acc0 = __builtin_amdgcn_mfma_f32_16x16x32_bf16(a0, bfv[ks], acc0, 0, 0, 0);
        acc1 = __builtin_amdgcn_mfma_f32_16x16x32_bf16(a1, bfv[ks], acc1, 0, 0, 0);
    }
    __syncthreads();                          // done reading xbf; reuse as transpose buf
    unsigned short* asT = xbf;                // [32 m][64 c]
    int c = nt * 16 + r;
    #pragma unroll
    for (int j = 0; j < 4; ++j) {
        int m0 = q * 4 + j;
        asT[m0 * 64 + c] = f2bf(acc0[j]);
        asT[(16 + m0) * 64 + c] = f2bf(acc1[j]);
    }
    __syncthreads();
    int b = bh >> 7, h = bh & 127;
    int ky = tid >> 4, idx8 = tid & 15;
    int ri = idx8 >> 3, c0 = (idx8 & 7) * 8;
    bf16x8 vv = *(const bf16x8*)&asT[(2 * ky + ri) * 64 + c0];
    *(bf16x8*)&X1[(((size_t)b * 16 + ky) * 128 + h) * 128 + ri * 64 + c0] = vv;
}

// ---------------- kB: DFT over h as GEMM [64 x 256] @ [256 x 64] per (b,ky) ----------------
__global__ __launch_bounds__(256) void kB(const unsigned short* __restrict__ X1, const unsigned short* __restrict__ FR,
                                          unsigned short* __restrict__ X2) {
    __shared__ unsigned short xb[256 * 64];   // 32 KB [k=2h+ri][c]
    int tid = threadIdx.x, blk = blockIdx.x;  // b*16 + ky
    int b = blk >> 4, ky = blk & 15;
    const unsigned short* p = X1 + ((size_t)b * 16 + ky) * 16384;
    for (int i = tid * 8; i < 256 * 64; i += 2048)
        *(bf16x8*)&xb[i] = *(const bf16x8*)&p[i];
    __syncthreads();
    const unsigned short* FB = FR + 4096;     // slot 512
    int lane = tid & 63, wid = tid >> 6, q = lane >> 4, r = lane & 15;
    int col = wid * 16 + r;
    bf16x8 bfv[8];
    #pragma unroll
    for (int ks = 0; ks < 8; ++ks) {
        short v[8];
        #pragma unroll
        for (int e = 0; e < 8; ++e)
            v[e] = (short)xb[(ks * 32 + q * 8 + e) * 64 + col];
        bfv[ks] = *(const bf16x8*)v;
    }
    f32x4 acc[4] = {{0.f,0.f,0.f,0.f},{0.f,0.f,0.f,0.f},{0.f,0.f,0.f,0.f},{0.f,0.f,0.f,0.f}};
    #pragma unroll
    for (int ks = 0; ks < 8; ++ks) {
        #pragma unroll
        for (int mt = 0; mt < 4; ++mt) {
            bf16x8 a = *(const bf16x8*)&FB[((size_t)((mt * 8 + ks) * 64 + lane)) * 8];
            acc[mt] = __builtin_amdgcn_mfma_f32_16x16x32_bf16(a, bfv[ks], acc[mt], 0, 0, 0);
        }
    }
    __syncthreads();                          // reuse xb head as transpose buf
    unsigned short* asT = xb;                 // [64 m=2kxi+rr][64 c]
    #pragma unroll
    for (int mt = 0; mt < 4; ++mt)
        #pragma unroll
        for (int j = 0; j < 4; ++j)
            asT[(mt * 16 + q * 4 + j) * 64 + col] = f2bf(acc[mt][j]);
    __syncthreads();
    int kxi = tid >> 3, part = tid & 7;
    short v2[16];
    #pragma unroll
    for (int s = 0; s < 16; ++s) {
        int n = part * 16 + s, cc2 = n >> 1, rr = n & 1;
        v2[s] = (short)asT[(2 * kxi + rr) * 64 + cc2];
    }
    unsigned short* dst = &X2[(((size_t)b * NKX + kxi) * 16 + ky) * 128 + part * 16];
    *(bf16x8*)&dst[0] = *(const bf16x8*)&v2[0];
    *(bf16x8*)&dst[8] = *(const bf16x8*)&v2[8];
}

// ---------------- kC: channel mix as GEMM [32 x 128] @ [128 x 128] per mode ----------------
__global__ __launch_bounds__(256) void kC(const float* __restrict__ w1r, const float* __restrict__ w1i,
                                          const float* __restrict__ w2r, const float* __restrict__ w2i,
                                          const unsigned short* __restrict__ X2, unsigned short* __restrict__ G) {
    __shared__ unsigned short wbr[CC * CC];   // 8 KB [i][o]
    __shared__ unsigned short wbi[CC * CC];   // 8 KB
    __shared__ unsigned short asT[32 * 128];  // 8 KB
    int tid = threadIdx.x;
    int blk = blockIdx.x;             // kxi*16 + ky
    int kxi = blk >> 4, ky = blk & 15;
    const float* wr = (kxi < 16) ? w1r : w2r;
    const float* wi = (kxi < 16) ? w1i : w2i;
    int wx = (kxi < 16) ? kxi : (kxi - 16);
    size_t woff = ((size_t)wx * MY + ky) * (CC * CC);
    for (int i = tid * 4; i < CC * CC; i += 1024) {
        float4 a = *(const float4*)&wr[woff + i];
        float4 bq = *(const float4*)&wi[woff + i];
        *(ushort4*)&wbr[i] = make_ushort4(f2bf(a.x), f2bf(a.y), f2bf(a.z), f2bf(a.w));
        *(ushort4*)&wbi[i] = make_ushort4(f2bf(bq.x), f2bf(bq.y), f2bf(bq.z), f2bf(bq.w));
    }
    __syncthreads();

    int lane = tid & 63, wid = tid >> 6;
    int q = lane >> 4, r = lane & 15;
    bf16x8 af[2][4];
    #pragma unroll
    for (int mt = 0; mt < 2; ++mt) {
        int b = mt * 16 + r;
        #pragma unroll
        for (int ks = 0; ks < 4; ++ks)
            af[mt][ks] = *(const bf16x8*)&X2[(((size_t)b * NKX + kxi) * 16 + ky) * 128 + ks * 32 + q * 8];
    }
    // B[k=2i+ri][n=2o+ro] = ri0: (wr, wi) ; ri1: (-wi, wr)
    bf16x8 bfr[2][4];
    #pragma unroll
    for (int t = 0; t < 2; ++t) {
        int n = (wid * 2 + t) * 16 + r;
        int o = n >> 1, ro = n & 1;
        #pragma unroll
        for (int ks = 0; ks < 4; ++ks) {
            short v[8];
            #pragma unroll
            for (int e = 0; e < 8; ++e) {
                int k = ks * 32 + q * 8 + e;
                int i = k >> 1, ri = k & 1;
                unsigned short raw = (ri == 0) ? (ro ? wbi[i * 64 + o] : wbr[i * 64 + o])
                                               : (ro ? wbr[i * 64 + o] : (unsigned short)(wbi[i * 64 + o] ^ 0x8000u));
                v[e] = (short)raw;
            }
            bfr[t][ks] = *(const bf16x8*)v;
        }
    }
    f32x4 acc[2][2] = {{{0.f,0.f,0.f,0.f},{0.f,0.f,0.f,0.f}},{{0.f,0.f,0.f,0.f},{0.f,0.f,0.f,0.f}}};
    #pragma unroll
    for (int ks = 0; ks < 4; ++ks)
        #pragma unroll
        for (int mt = 0; mt < 2; ++mt)
            #pragma unroll
            for (int t = 0; t < 2; ++t)
                acc[mt][t] = __builtin_amdgcn_mfma_f32_16x16x32_bf16(af[mt][ks], bfr[t][ks], acc[mt][t], 0, 0, 0);
    #pragma unroll
    for (int mt = 0; mt < 2; ++mt)
        #pragma unroll
        for (int t = 0; t < 2; ++t)
            #pragma unroll
            for (int j = 0; j < 4; ++j)
                asT[(mt * 16 + q * 4 + j) * 128 + (wid * 2 + t) * 16 + r] = f2bf(acc[mt][t][j]);
    __syncthreads();
    int bb = tid >> 3, part = tid & 7;
    bf16x8 u0 = *(const bf16x8*)&asT[bb * 128 + part * 16];
    bf16x8 u1 = *(const bf16x8*)&asT[bb * 128 + part * 16 + 8];
    unsigned short* dst = &G[(((size_t)bb * NKX + kxi) * 16 + ky) * 128 + part * 16];
    *(bf16x8*)&dst[0] = u0;
    *(bf16x8*)&dst[8] = u1;
}

// ---------------- kD: inverse DFT over kx, writes Z in kE fragment layout ----------------
__global__ __launch_bounds__(256) void kD(const unsigned short* __restrict__ G, const unsigned short* __restrict__ FR,
                                          unsigned short* __restrict__ Zf) {
    __shared__ unsigned short gs[NKX * 128];   // 8 KB
    int tid = threadIdx.x, blk = blockIdx.x;   // b*32 + ky*2 + mh
    int b = blk >> 5, ky = (blk >> 1) & 15, mh = blk & 1;
    for (int i = tid * 8; i < NKX * 128; i += 2048) {
        int kxi = i >> 7, n = i & 127;
        *(bf16x8*)&gs[i] = *(const bf16x8*)&G[(((size_t)b * NKX + kxi) * 16 + ky) * 128 + n];
    }
    __syncthreads();
    int lane = tid & 63, wid = tid >> 6, q = lane >> 4, r = lane & 15;
    const unsigned short* FD = FR + 20480;     // slot 2560
    // B[k=2kxi+ri][n=2c+ro] = gs[kxi][n ^ ri], negated iff ri & (n&1)
    bf16x8 bfr[2][2];
    #pragma unroll
    for (int t = 0; t < 2; ++t) {
        int n = (wid * 2 + t) * 16 + r;
        #pragma unroll
        for (int ks = 0; ks < 2; ++ks) {
            short v[8];
            #pragma unroll
            for (int e = 0; e < 8; ++e) {
                int k = ks * 32 + q * 8 + e;
                int kxi = k >> 1, ri = k & 1;
                unsigned short raw = gs[kxi * 128 + (n ^ ri)];
                if (ri & (n & 1)) raw ^= 0x8000u;
                v[e] = (short)raw;
            }
            bfr[t][ks] = *(const bf16x8*)v;
        }
    }
    #pragma unroll
    for (int mt2 = 0; mt2 < 4; ++mt2) {
        int mt = mh * 4 + mt2;
        f32x4 acc[2] = {{0.f,0.f,0.f,0.f},{0.f,0.f,0.f,0.f}};
        #pragma unroll
        for (int ks = 0; ks < 2; ++ks) {
            bf16x8 a = *(const bf16x8*)&FD[((size_t)((mt * 2 + ks) * 64 + lane)) * 8];
            #pragma unroll
            for (int t = 0; t < 2; ++t)
                acc[t] = __builtin_amdgcn_mfma_f32_16x16x32_bf16(a, bfr[t][ks], acc[t], 0, 0, 0);
        }
        #pragma unroll
        for (int t = 0; t < 2; ++t)
            #pragma unroll
            for (int j = 0; j < 4; ++j) {
                int h = mt * 16 + q * 4 + j;
                int n = (wid * 2 + t) * 16 + r;
                int c = n >> 1, reim = n & 1;
                int kp = 2 * ky + reim, q2 = kp >> 3, e2 = kp & 7;
                int nt2 = c >> 4, r2 = c & 15;
                Zf[(((size_t)b * 128 + h) * 4 + nt2) * 512 + (q2 * 16 + r2) * 8 + e2] = f2bf(acc[t][j]);
            }
    }
}

// ---------------- kE: MFMA GEMM  out = GELU(x + [x|T]@[K;Z] + bias), x from Xbf ----------------
__global__ __launch_bounds__(256) void kE(const unsigned short* __restrict__ Xbf, const unsigned short* __restrict__ Zf,
                                          const unsigned short* __restrict__ FR,
                                          const float* __restrict__ bias, float* __restrict__ out) {
    __shared__ unsigned short xs16[WW * 72];   // 18 KB, stride 72 keeps b128 aligned, <=2-way banks
    int tid = threadIdx.x, bh = blockIdx.x;
    const unsigned short* xp = Xbf + (size_t)bh * (WW * CC);
    for (int i = tid * 8; i < WW * CC; i += 2048) {
        int w = i >> 6, c = i & 63;
        *(bf16x8*)&xs16[w * 72 + c] = *(const bf16x8*)&xp[i];
    }
    __syncthreads();
    int lane = tid & 63, wv = tid >> 6, q = lane >> 4, r = lane & 15;
    const unsigned short* FEAT = FR + 28672;   // slot 3584
    const unsigned short* FEBK = FR + 32768;   // slot 4096
    bf16x8 ax[2][2], at[2];
    #pragma unroll
    for (int t2 = 0; t2 < 2; ++t2) {
        int tm = wv * 2 + t2;
        int row = tm * 16 + r;
        #pragma unroll
        for (int ks = 0; ks < 2; ++ks)
            ax[t2][ks] = *(const bf16x8*)&xs16[row * 72 + ks * 32 + q * 8];
        at[t2] = *(const bf16x8*)&FEAT[((size_t)(tm * 64 + lane)) * 8];
    }
    #pragma unroll
    for (int nt = 0; nt < 4; ++nt) {
        bf16x8 b0 = *(const bf16x8*)&FEBK[((size_t)((nt * 2 + 0) * 64 + lane)) * 8];
        bf16x8 b1 = *(const bf16x8*)&FEBK[((size_t)((nt * 2 + 1) * 64 + lane)) * 8];
        bf16x8 bz = *(const bf16x8*)&Zf[((size_t)bh * 4 + nt) * 512 + lane * 8];
        int c = nt * 16 + r;
        float bsv = bias[c];
        #pragma unroll
        for (int t2 = 0; t2 < 2; ++t2) {
            int tm = wv * 2 + t2;
            f32x4 acc = {0.f, 0.f, 0.f, 0.f};
            acc = __builtin_amdgcn_mfma_f32_16x16x32_bf16(ax[t2][0], b0, acc, 0, 0, 0);
            acc = __builtin_amdgcn_mfma_f32_16x16x32_bf16(ax[t2][1], b1, acc, 0, 0, 0);
            acc = __builtin_amdgcn_mfma_f32_16x16x32_bf16(at[t2], bz, acc, 0, 0, 0);
            #pragma unroll
            for (int j = 0; j < 4; ++j) {
                int w = tm * 16 + q * 4 + j;
                float u = acc[j] + bf2f(xs16[w * 72 + c]) + bsv;
                float t = u + 0.044715f * u * u * u;
                float e = __expf(-1.5957691216057308f * t);
                out[(size_t)bh * (WW * CC) + w * CC + c] = u / (1.0f + e);
            }
        }
    }
}

extern "C" void kernel_launch(void* const* d_in, const int* in_sizes, int n_in,
                              void* d_out, int out_size, void* d_ws, size_t ws_size,
                              hipStream_t stream) {
    const float* x   = (const float*)d_in[0];
    const float* w1r = (const float*)d_in[1];
    const float* w1i = (const float*)d_in[2];
    const float* w2r = (const float*)d_in[3];
    const float* w2i = (const float*)d_in[4];
    const float* dk  = (const float*)d_in[5];
    const float* db  = (const float*)d_in[6];
    float* out = (float*)d_out;

    unsigned short* FR  = (unsigned short*)d_ws;     // 4608*8 shorts, padded to 128 KB
    unsigned short* X1  = FR + 65536;                // 8,388,608 elems
    unsigned short* X2  = X1 + 8388608;              // 2,097,152 elems
    unsigned short* G   = X2 + 2097152;              // 2,097,152 elems
    unsigned short* Zf  = G  + 2097152;              // 8,388,608 elems
    unsigned short* Xbf = Zf + 8388608;              // 8,388,608 elems

    kT<<<18, 256, 0, stream>>>(dk, FR);
    kA<<<BB * HH, 256, 0, stream>>>(x, FR, X1, Xbf);
    kB<<<BB * MY, 256, 0, stream>>>(X1, FR, X2);
    kC<<<NKX * MY, 256, 0, stream>>>(w1r, w1i, w2r, w2i, X2, G);
    kD<<<BB * MY * 2, 256, 0, stream>>>(G, FR, Zf);
    kE<<<BB * HH, 256, 0, stream>>>(Xbf, Zf, FR, db, out);
}